// Round 7
// baseline (161.212 us; speedup 1.0000x reference)
//
#include <hip/hip_runtime.h>

#define B_  16
#define LC  2048
#define LQ  512
#define DD  128
#define L2E 1.44269504088896340736f
#define SP  16

typedef __attribute__((ext_vector_type(8))) short bf16x8;
typedef __attribute__((ext_vector_type(4))) float f32x4;
typedef unsigned short u16;
typedef unsigned int   u32;

#define MFMA(a,b,c) __builtin_amdgcn_mfma_f32_16x16x32_bf16((a),(b),(c),0,0,0)

__device__ __forceinline__ u16 f2bf(float x){
  u32 u = __builtin_bit_cast(u32, x);
  u32 r = (u + 0x7FFFu + ((u >> 16) & 1u)) >> 16;
  return (u16)r;
}
__device__ __forceinline__ float bf2f(u16 h){
  u32 u = ((u32)h) << 16;
  return __builtin_bit_cast(float, u);
}
__device__ __forceinline__ bf16x8 ldb8(const u16* p){
  return *reinterpret_cast<const bf16x8*>(p);
}
// swizzled LDS read addr for a [rows][256B] tile: byte ^= (row&7)<<4
__device__ __forceinline__ const u16* swz(const u16* base, int row, int colb){
  return base + (row << 7) + ((colb ^ ((row & 7) << 4)) >> 1);
}
#define GLOAD_LDS(g, l) \
  __builtin_amdgcn_global_load_lds((const __attribute__((address_space(1))) void*)(g), \
                                   (__attribute__((address_space(3))) void*)(l), 16, 0, 0)

// ---------------- K0: bf16 staging + transposes + row-dots ----------------
__global__ void prep(const float* __restrict__ C, const float* __restrict__ Q,
                     const float* __restrict__ w4C, const float* __restrict__ w4Q,
                     const float* __restrict__ w4mlu,
                     u16* __restrict__ Cb,  u16* __restrict__ CbT,
                     u16* __restrict__ Qwb, u16* __restrict__ QbT,
                     float* __restrict__ sub0, float* __restrict__ sub1){
  __shared__ u16 tile[64][130];
  __shared__ float wl[128];
  int t = threadIdx.x, blk = blockIdx.x;
  int lane = t & 63;
  bool isC = blk < 512;
  if (t < 128) wl[t] = w4mlu[t];
  __syncthreads();
  float2 wv = reinterpret_cast<const float2*>(isC ? w4C : w4Q)[lane];
  if (isC) {
    int b = blk >> 5, ct = blk & 31, c0 = ct << 6;
    const float* src = C + ((size_t)(b*LC + c0))*DD;
    for (int k = 0; k < 16; ++k) {
      int idx = t + (k << 8);
      int r = idx >> 6, d2 = idx & 63;
      float2 v = reinterpret_cast<const float2*>(src + (size_t)r*DD)[d2];
      float sdot = v.x*wv.x + v.y*wv.y;
      #pragma unroll
      for (int o = 32; o > 0; o >>= 1) sdot += __shfl_xor(sdot, o);
      if (lane == 0) sub0[b*LC + c0 + r] = sdot;
      u16 h0 = f2bf(v.x), h1 = f2bf(v.y);
      size_t o = ((size_t)(b*LC + c0 + r))*DD + 2*d2;
      *reinterpret_cast<u32*>(Cb + o) = (u32)h0 | ((u32)h1 << 16);
      tile[r][2*d2]   = h0;
      tile[r][2*d2+1] = h1;
    }
    __syncthreads();
    for (int k = 0; k < 8; ++k) {
      int ch = t + (k << 8);
      int d = ch >> 4, c4 = (ch & 15) << 2;
      u32 lo = (u32)tile[c4][d]   | ((u32)tile[c4+1][d] << 16);
      u32 hi = (u32)tile[c4+2][d] | ((u32)tile[c4+3][d] << 16);
      uint2 u; u.x = lo; u.y = hi;
      *reinterpret_cast<uint2*>(CbT + ((size_t)(b*DD + d))*LC + c0 + c4) = u;
    }
  } else {
    int bq = blk - 512;
    int b = bq >> 3, qt = bq & 7, q0 = qt << 6;
    const float* src = Q + ((size_t)(b*LQ + q0))*DD;
    for (int k = 0; k < 16; ++k) {
      int idx = t + (k << 8);
      int r = idx >> 6, d2 = idx & 63;
      float2 v = reinterpret_cast<const float2*>(src + (size_t)r*DD)[d2];
      float sdot = v.x*wv.x + v.y*wv.y;
      #pragma unroll
      for (int o = 32; o > 0; o >>= 1) sdot += __shfl_xor(sdot, o);
      if (lane == 0) sub1[b*LQ + q0 + r] = sdot;
      float qw0 = v.x * wl[2*d2], qw1 = v.y * wl[2*d2+1];
      size_t o = ((size_t)(b*LQ + q0 + r))*DD + 2*d2;
      *reinterpret_cast<u32*>(Qwb + o) = (u32)f2bf(qw0) | ((u32)f2bf(qw1) << 16);
      tile[r][2*d2]   = f2bf(v.x);
      tile[r][2*d2+1] = f2bf(v.y);
    }
    __syncthreads();
    for (int k = 0; k < 8; ++k) {
      int ch = t + (k << 8);
      int d = ch >> 4, c4 = (ch & 15) << 2;
      u32 lo = (u32)tile[c4][d]   | ((u32)tile[c4+1][d] << 16);
      u32 hi = (u32)tile[c4+2][d] | ((u32)tile[c4+3][d] << 16);
      uint2 u; u.x = lo; u.y = hi;
      *reinterpret_cast<uint2*>(QbT + ((size_t)(b*DD + d))*LQ + q0 + c4) = u;
    }
  }
}

// ---------------- K1: flash column-softmax -> partial T ----------------
__global__ __launch_bounds__(256, 3)
void flashT(const u16* __restrict__ Qwb, const u16* __restrict__ Cb,
            const u16* __restrict__ CbT, const float* __restrict__ sub0,
            float* __restrict__ mPart, float* __restrict__ lPart,
            u16* __restrict__ TaccP){
  __shared__ __align__(16) u16 buf[128*128];
  __shared__ u16 Pl[64][136];
  int bid = blockIdx.x;
  int id = (bid & 7) * 256 + (bid >> 3);
  int b = id >> 7, qb = (id >> 4) & 7, sp = id & 15;
  int c0 = sp * 128;
  int w = threadIdx.x >> 6, l = threadIdx.x & 63;
  int lj = l & 15, lg = l >> 4;

  {
    const char* gb = (const char*)(Cb + ((size_t)(b*LC + c0))*DD);
    #pragma unroll
    for (int i = 0; i < 8; ++i) {
      int off = (w*8 + i)*1024 + l*16;
      int row = off >> 8, col = off & 255;
      int src = (row << 8) | (col ^ ((row & 7) << 4));
      GLOAD_LDS(gb + src, (char*)buf + off);
    }
  }
  const u16* Qrow = Qwb + ((size_t)(b*LQ + qb*64 + w*16 + lj))*DD;
  bf16x8 aq[4];
  #pragma unroll
  for (int k = 0; k < 4; ++k) aq[k] = ldb8(Qrow + k*32 + lg*8);
  float s0v[8];
  #pragma unroll
  for (int f = 0; f < 8; ++f) s0v[f] = sub0[b*LC + c0 + f*16 + lj];
  __syncthreads();

  f32x4 s[8];
  #pragma unroll
  for (int f = 0; f < 8; ++f) s[f] = (f32x4){0.f,0.f,0.f,0.f};
  #pragma unroll
  for (int ks = 0; ks < 4; ++ks) {
    #pragma unroll
    for (int f = 0; f < 8; ++f)
      s[f] = MFMA(aq[ks], ldb8(swz(buf, f*16 + lj, ks*64 + lg*16)), s[f]);
  }
  __syncthreads();

  {
    const char* gb = (const char*)CbT + ((size_t)b*DD)*LC*2 + (size_t)c0*2;
    #pragma unroll
    for (int i = 0; i < 8; ++i) {
      int off = (w*8 + i)*1024 + l*16;
      int row = off >> 8, col = off & 255;
      size_t src = (size_t)row*(LC*2) + (col ^ ((row & 7) << 4));
      GLOAD_LDS(gb + src, (char*)buf + off);
    }
  }

  float tm[4] = {-1e30f,-1e30f,-1e30f,-1e30f};
  #pragma unroll
  for (int f = 0; f < 8; ++f) {
    #pragma unroll
    for (int r = 0; r < 4; ++r) { s[f][r] += s0v[f]; tm[r] = fmaxf(tm[r], s[f][r]); }
  }
  #pragma unroll
  for (int r = 0; r < 4; ++r) {
    #pragma unroll
    for (int m = 1; m < 16; m <<= 1) tm[r] = fmaxf(tm[r], __shfl_xor(tm[r], m));
  }
  float psum[4] = {0.f,0.f,0.f,0.f};
  #pragma unroll
  for (int f = 0; f < 8; ++f) {
    #pragma unroll
    for (int r = 0; r < 4; ++r) {
      float p = exp2f((s[f][r] - tm[r]) * L2E);
      psum[r] += p;
      Pl[w*16 + lg*4 + r][f*16 + lj] = f2bf(p);
    }
  }
  #pragma unroll
  for (int r = 0; r < 4; ++r) {
    #pragma unroll
    for (int m = 1; m < 16; m <<= 1) psum[r] += __shfl_xor(psum[r], m);
  }
  int pbase = (b*8 + qb)*SP + sp;
  if (lj == 0) {
    #pragma unroll
    for (int r = 0; r < 4; ++r) {
      mPart[pbase*64 + w*16 + lg*4 + r] = tm[r];
      lPart[pbase*64 + w*16 + lg*4 + r] = psum[r];
    }
  }
  __syncthreads();

  f32x4 tacc[8];
  #pragma unroll
  for (int f = 0; f < 8; ++f) tacc[f] = (f32x4){0.f,0.f,0.f,0.f};
  #pragma unroll
  for (int ks = 0; ks < 4; ++ks) {
    bf16x8 ap = *reinterpret_cast<const bf16x8*>(&Pl[w*16 + lj][ks*32 + lg*8]);
    #pragma unroll
    for (int f = 0; f < 8; ++f)
      tacc[f] = MFMA(ap, ldb8(swz(buf, f*16 + lj, ks*64 + lg*16)), tacc[f]);
  }
  #pragma unroll
  for (int f = 0; f < 8; ++f) {
    ushort4 hv;
    hv.x = f2bf(tacc[f][0]); hv.y = f2bf(tacc[f][1]);
    hv.z = f2bf(tacc[f][2]); hv.w = f2bf(tacc[f][3]);
    *reinterpret_cast<ushort4*>(TaccP + (((size_t)pbase*4 + w)*8 + f)*256 + lj*16 + lg*4) = hv;
  }
}

// ---------------- K1b: combine c-split partials -> TbT ----------------
__global__ void combineT(const float* __restrict__ mPart, const float* __restrict__ lPart,
                         const u16* __restrict__ TaccP, u16* __restrict__ TbT){
  __shared__ float fac[SP][64];
  __shared__ u16 Tt[64][68];
  int blk = blockIdx.x;
  int b = blk >> 4, qb = (blk >> 1) & 7, dh = blk & 1;
  int t = threadIdx.x;
  int base = (b*8 + qb)*SP;
  if (t < 64) {
    float m_[SP], mm = -1e30f;
    #pragma unroll
    for (int p = 0; p < SP; ++p) { m_[p] = mPart[(base+p)*64 + t]; mm = fmaxf(mm, m_[p]); }
    float lt = 0.f, e[SP];
    #pragma unroll
    for (int p = 0; p < SP; ++p) {
      e[p] = exp2f((m_[p] - mm) * L2E);
      lt += lPart[(base+p)*64 + t] * e[p];
    }
    float il = 1.0f / lt;
    #pragma unroll
    for (int p = 0; p < SP; ++p) fac[p][t] = e[p] * il;
  }
  __syncthreads();
  int lj = t >> 4, lg = (t >> 2) & 3, r = t & 3;
  for (int w = 0; w < 4; ++w) {
    int q = w*16 + lg*4 + r;
    for (int fi = 0; fi < 4; ++fi) {
      int f = dh*4 + fi;
      float acc = 0.f;
      #pragma unroll
      for (int p = 0; p < SP; ++p)
        acc += bf2f(TaccP[(((size_t)(base+p)*4 + w)*8 + f)*256 + t]) * fac[p][q];
      Tt[q][fi*16 + lj] = f2bf(acc);
    }
  }
  __syncthreads();
  for (int k = 0; k < 4; ++k) {
    int ch = t + (k << 8); int dl = ch >> 4, q4 = (ch & 15) << 2;
    u32 lo = (u32)Tt[q4][dl]   | ((u32)Tt[q4+1][dl] << 16);
    u32 hi = (u32)Tt[q4+2][dl] | ((u32)Tt[q4+3][dl] << 16);
    uint2 u; u.x = lo; u.y = hi;
    *reinterpret_cast<uint2*>(TbT + ((size_t)(b*DD + dh*64 + dl))*LQ + qb*64 + q4) = u;
  }
}

// ---------------- K2: row-softmax + A + Bt + epilogue (single kernel) ------
// grid 1024 = 16 b x 64 ctiles(32 c). 4 waves. Reg-staged single 16KB buffer.
// Phase I: S^T = Qw·Cb^T (8 q-chunks). Phase II: softmax -> Plq (normalized).
// Phase III: A = P·Q (QbT chunks). Phase IV: Bt = P·T (TbT chunks). Epilogue.
__global__ __launch_bounds__(256, 3)
void rowsm_all(const float* __restrict__ Cf, const u16* __restrict__ Cb,
               const u16* __restrict__ Qwb, const u16* __restrict__ QbT,
               const u16* __restrict__ TbT, const float* __restrict__ sub1,
               float* __restrict__ out){
  __shared__ __align__(16) char smem[50176];
  char*  stg  = smem;                    // 16 KB chunk buffer
  char*  PlqB = smem + 16384;            // [32 c][1024B] swz16, 32 KB
  float* redM = (float*)(smem + 49152);  // [4][32]
  float* redS = redM + 128;              // [4][32]

  int bid = blockIdx.x;
  int id = (bid & 7) * 128 + (bid >> 3);   // XCD swizzle, nwg=1024
  int b = id >> 6, ct = id & 63, c0 = ct * 32;
  int tid = threadIdx.x;
  int w = tid >> 6, l = tid & 63;
  int lj = l & 15, lg = l >> 4;

  // one-time Cb B-fragments via direct global gathers (L2-resident)
  bf16x8 ca[2][4];
  #pragma unroll
  for (int cf = 0; cf < 2; ++cf)
    #pragma unroll
    for (int ks = 0; ks < 4; ++ks)
      ca[cf][ks] = ldb8(Cb + ((size_t)(b*LC + c0 + cf*16 + lj))*DD + ks*32 + lg*8);

  const char* gQw = (const char*)Qwb + (size_t)b*LQ*256;
  const char* gQt = (const char*)QbT + (size_t)b*DD*1024;
  const char* gTt = (const char*)TbT + (size_t)b*DD*1024;

  // stage Qw chunk 0 (reg -> LDS, 16-way swizzle on [64 q][256B])
  uint4 rv[4];
  #pragma unroll
  for (int i = 0; i < 4; ++i)
    rv[i] = *(const uint4*)(gQw + i*4096 + tid*16);
  #pragma unroll
  for (int i = 0; i < 4; ++i) {
    int off = i*4096 + tid*16, row = off >> 8, col = off & 255;
    *(uint4*)(stg + row*256 + (col ^ ((row & 15) << 4))) = rv[i];
  }
  __syncthreads();

  // ---- phase I: S^T chunks (8 x 64 q). D[col=c][row=q].
  f32x4 s[8][2];
  #pragma unroll
  for (int ch = 0; ch < 8; ++ch)
    #pragma unroll
    for (int cf = 0; cf < 2; ++cf) s[ch][cf] = (f32x4){0.f,0.f,0.f,0.f};

  #pragma unroll
  for (int ch = 0; ch < 8; ++ch) {
    if (ch < 7) {
      #pragma unroll
      for (int i = 0; i < 4; ++i)
        rv[i] = *(const uint4*)(gQw + (ch+1)*16384 + i*4096 + tid*16);
    }
    int q_ = w*16 + lj;                      // (q_&15)==lj
    bf16x8 aq[4];
    #pragma unroll
    for (int ks = 0; ks < 4; ++ks)
      aq[ks] = ldb8((const u16*)(stg + q_*256 + ((ks*64 + lg*16) ^ (lj << 4))));
    #pragma unroll
    for (int ks = 0; ks < 4; ++ks)
      #pragma unroll
      for (int cf = 0; cf < 2; ++cf)
        s[ch][cf] = MFMA(aq[ks], ca[cf][ks], s[ch][cf]);
    if (ch < 7) {
      __syncthreads();
      #pragma unroll
      for (int i = 0; i < 4; ++i) {
        int off = i*4096 + tid*16, row = off >> 8, col = off & 255;
        *(uint4*)(stg + row*256 + (col ^ ((row & 15) << 4))) = rv[i];
      }
      __syncthreads();
    }
  }

  // early-issue QbT chunk 0 loads (latency hides under softmax)
  #pragma unroll
  for (int i = 0; i < 4; ++i) {
    int off = i*4096 + tid*16, row = off >> 7, col = off & 127;
    rv[i] = *(const uint4*)(gQt + (size_t)row*1024 + col);
  }

  // ---- phase II: row-softmax over q (lane cols c = cf*16+lj)
  float tm[2] = {-1e30f, -1e30f};
  #pragma unroll
  for (int ch = 0; ch < 8; ++ch) {
    f32x4 sv = *(const f32x4*)(sub1 + b*LQ + ch*64 + w*16 + lg*4);
    #pragma unroll
    for (int cf = 0; cf < 2; ++cf) {
      s[ch][cf] += sv;
      #pragma unroll
      for (int r = 0; r < 4; ++r) tm[cf] = fmaxf(tm[cf], s[ch][cf][r]);
    }
  }
  #pragma unroll
  for (int cf = 0; cf < 2; ++cf) {
    tm[cf] = fmaxf(tm[cf], __shfl_xor(tm[cf], 16));
    tm[cf] = fmaxf(tm[cf], __shfl_xor(tm[cf], 32));
  }
  if (lg == 0) { redM[w*32 + lj] = tm[0]; redM[w*32 + 16 + lj] = tm[1]; }
  __syncthreads();
  float mfin[2];
  #pragma unroll
  for (int cf = 0; cf < 2; ++cf) {
    int c = cf*16 + lj;
    mfin[cf] = fmaxf(fmaxf(redM[c], redM[32 + c]), fmaxf(redM[64 + c], redM[96 + c]));
  }
  float ps[2] = {0.f, 0.f};
  #pragma unroll
  for (int ch = 0; ch < 8; ++ch)
    #pragma unroll
    for (int cf = 0; cf < 2; ++cf)
      #pragma unroll
      for (int r = 0; r < 4; ++r) {
        float p = exp2f((s[ch][cf][r] - mfin[cf]) * L2E);
        s[ch][cf][r] = p;
        ps[cf] += p;
      }
  #pragma unroll
  for (int cf = 0; cf < 2; ++cf) {
    ps[cf] += __shfl_xor(ps[cf], 16);
    ps[cf] += __shfl_xor(ps[cf], 32);
  }
  if (lg == 0) { redS[w*32 + lj] = ps[0]; redS[w*32 + 16 + lj] = ps[1]; }
  __syncthreads();
  float linv[2];
  #pragma unroll
  for (int cf = 0; cf < 2; ++cf) {
    int c = cf*16 + lj;
    linv[cf] = 1.0f / (redS[c] + redS[32 + c] + redS[64 + c] + redS[96 + c]);
  }
  // pack normalized P -> Plq (ushort4 per (ch,cf); conflict-free: 16 lj -> 16 slots)
  #pragma unroll
  for (int ch = 0; ch < 8; ++ch)
    #pragma unroll
    for (int cf = 0; cf < 2; ++cf) {
      ushort4 hv;
      hv.x = f2bf(s[ch][cf][0] * linv[cf]);
      hv.y = f2bf(s[ch][cf][1] * linv[cf]);
      hv.z = f2bf(s[ch][cf][2] * linv[cf]);
      hv.w = f2bf(s[ch][cf][3] * linv[cf]);
      int c = cf*16 + lj;
      int qb = ch*128 + w*32 + lg*8;
      *(ushort4*)(PlqB + c*1024 + (qb ^ (lj << 4))) = hv;
    }
  // write staged QbT chunk 0 (stg reads all retired at redM barrier)
  #pragma unroll
  for (int i = 0; i < 4; ++i) {
    int off = i*4096 + tid*16, row = off >> 7, col = off & 127;
    *(uint4*)(stg + row*128 + (col ^ ((row & 7) << 4))) = rv[i];
  }
  __syncthreads();   // Plq + stg chunk0 visible

  // ---- phases III & IV: A = P·Q then Bt = P·T, chunked over q
  f32x4 aA[2][2], aB[2][2];
  #pragma unroll
  for (int cmf = 0; cmf < 2; ++cmf)
    #pragma unroll
    for (int cf = 0; cf < 2; ++cf) { aA[cmf][cf] = (f32x4){0.f,0.f,0.f,0.f}; aB[cmf][cf] = (f32x4){0.f,0.f,0.f,0.f}; }

  #pragma unroll
  for (int ph = 0; ph < 2; ++ph) {
    #pragma unroll
    for (int ch = 0; ch < 8; ++ch) {
      bool more = (ph == 0) || (ch < 7);
      if (more) {
        const char* gsrc = (ph == 0) ? ((ch < 7) ? gQt : gTt) : gTt;
        int chn = (ph == 0 && ch < 7) ? (ch+1) : ((ph == 0) ? 0 : ch+1);
        #pragma unroll
        for (int i = 0; i < 4; ++i) {
          int off = i*4096 + tid*16, row = off >> 7, col = off & 127;
          rv[i] = *(const uint4*)(gsrc + (size_t)row*1024 + chn*128 + col);
        }
      }
      // A-frags from Plq (rows c), B-frags from stg (rows d)
      bf16x8 pa[2][2], bv[2][2];
      #pragma unroll
      for (int ks = 0; ks < 2; ++ks) {
        #pragma unroll
        for (int cmf = 0; cmf < 2; ++cmf) {
          int c = cmf*16 + lj;
          int qb = ch*128 + ks*64 + lg*16;
          pa[cmf][ks] = ldb8((const u16*)(PlqB + c*1024 + (qb ^ (lj << 4))));
        }
        #pragma unroll
        for (int cf = 0; cf < 2; ++cf) {
          int d = w*32 + cf*16 + lj;
          bv[cf][ks] = ldb8((const u16*)(stg + d*128 + ((ks*64 + lg*16) ^ ((d & 7) << 4))));
        }
      }
      if (ph == 0) {
        #pragma unroll
        for (int ks = 0; ks < 2; ++ks)
          #pragma unroll
          for (int cmf = 0; cmf < 2; ++cmf)
            #pragma unroll
            for (int cf = 0; cf < 2; ++cf)
              aA[cmf][cf] = MFMA(pa[cmf][ks], bv[cf][ks], aA[cmf][cf]);
      } else {
        #pragma unroll
        for (int ks = 0; ks < 2; ++ks)
          #pragma unroll
          for (int cmf = 0; cmf < 2; ++cmf)
            #pragma unroll
            for (int cf = 0; cf < 2; ++cf)
              aB[cmf][cf] = MFMA(pa[cmf][ks], bv[cf][ks], aB[cmf][cf]);
      }
      if (more) {
        __syncthreads();
        #pragma unroll
        for (int i = 0; i < 4; ++i) {
          int off = i*4096 + tid*16, row = off >> 7, col = off & 127;
          *(uint4*)(stg + row*128 + (col ^ ((row & 7) << 4))) = rv[i];
        }
        __syncthreads();
      }
    }
  }

  // ---- epilogue: all 4 segments
  #pragma unroll
  for (int cmf = 0; cmf < 2; ++cmf)
    #pragma unroll
    for (int cf = 0; cf < 2; ++cf)
      #pragma unroll
      for (int r = 0; r < 4; ++r) {
        int c = c0 + cmf*16 + lg*4 + r;
        int d = w*32 + cf*16 + lj;
        float Cv = Cf[((size_t)(b*LC + c))*DD + d];
        float Av = aA[cmf][cf][r];
        float Bv = aB[cmf][cf][r];
        size_t ob = ((size_t)(b*LC + c))*512;
        out[ob + d]       = Cv;
        out[ob + 128 + d] = Av;
        out[ob + 256 + d] = Cv*Av;
        out[ob + 384 + d] = Cv*Bv;
      }
}

// ---------------- launch ----------------
extern "C" void kernel_launch(void* const* d_in, const int* in_sizes, int n_in,
                              void* d_out, int out_size, void* d_ws, size_t ws_size,
                              hipStream_t stream) {
  const float* C     = (const float*)d_in[0];
  const float* Q     = (const float*)d_in[1];
  const float* w4C   = (const float*)d_in[4];
  const float* w4Q   = (const float*)d_in[5];
  const float* w4mlu = (const float*)d_in[6];
  float* out = (float*)d_out;

  char* ws = (char*)d_ws;
  size_t off = 0;
  auto alloc = [&](size_t bytes) -> void* {
    void* p = ws + off;
    off += (bytes + 255) & ~(size_t)255;
    return p;
  };
  float* sub0  = (float*)alloc((size_t)B_*LC*4);
  float* sub1  = (float*)alloc((size_t)B_*LQ*4);
  u16*   Cb    = (u16*)  alloc((size_t)B_*LC*DD*2);
  u16*   CbT   = (u16*)  alloc((size_t)B_*DD*LC*2);
  u16*   Qwb   = (u16*)  alloc((size_t)B_*LQ*DD*2);
  u16*   QbT   = (u16*)  alloc((size_t)B_*DD*LQ*2);
  u16*   TbT   = (u16*)  alloc((size_t)B_*DD*LQ*2);
  float* mPart = (float*)alloc((size_t)B_*8*SP*64*4);
  float* lPart = (float*)alloc((size_t)B_*8*SP*64*4);
  u16*   TaccP = (u16*)  alloc((size_t)B_*8*SP*64*DD*2);

  hipLaunchKernelGGL(prep, dim3(640), dim3(256), 0, stream,
                     C, Q, w4C, w4Q, w4mlu, Cb, CbT, Qwb, QbT, sub0, sub1);
  hipLaunchKernelGGL(flashT, dim3(2048), dim3(256), 0, stream,
                     Qwb, Cb, CbT, sub0, mPart, lPart, TaccP);
  hipLaunchKernelGGL(combineT, dim3(256), dim3(256), 0, stream,
                     mPart, lPart, TaccP, TbT);
  hipLaunchKernelGGL(rowsm_all, dim3(1024), dim3(256), 0, stream,
                     C, Cb, Qwb, QbT, TbT, sub1, out);
}

// Round 8
// 85.984 us; speedup vs baseline: 1.8749x; 1.8749x over previous
//
#include <hip/hip_runtime.h>

#define B_  16
#define LC  2048
#define LQ  512
#define DD  128
#define L2E 1.44269504088896340736f
#define SP  16

typedef __attribute__((ext_vector_type(8))) short bf16x8;
typedef __attribute__((ext_vector_type(4))) float f32x4;
typedef unsigned short u16;
typedef unsigned int   u32;

#define MFMA(a,b,c) __builtin_amdgcn_mfma_f32_16x16x32_bf16((a),(b),(c),0,0,0)

__device__ __forceinline__ u16 f2bf(float x){
  u32 u = __builtin_bit_cast(u32, x);
  u32 r = (u + 0x7FFFu + ((u >> 16) & 1u)) >> 16;
  return (u16)r;
}
__device__ __forceinline__ float bf2f(u16 h){
  u32 u = ((u32)h) << 16;
  return __builtin_bit_cast(float, u);
}
__device__ __forceinline__ bf16x8 ldb8(const u16* p){
  return *reinterpret_cast<const bf16x8*>(p);
}
// swizzled LDS read addr for a [rows][256B] tile: byte ^= (row&7)<<4
__device__ __forceinline__ const u16* swz(const u16* base, int row, int colb){
  return base + (row << 7) + ((colb ^ ((row & 7) << 4)) >> 1);
}
#define GLOAD_LDS(g, l) \
  __builtin_amdgcn_global_load_lds((const __attribute__((address_space(1))) void*)(g), \
                                   (__attribute__((address_space(3))) void*)(l), 16, 0, 0)

// ---------------- K0: bf16 staging + transposes + row-dots ----------------
__global__ void prep(const float* __restrict__ C, const float* __restrict__ Q,
                     const float* __restrict__ w4C, const float* __restrict__ w4Q,
                     const float* __restrict__ w4mlu,
                     u16* __restrict__ Cb,  u16* __restrict__ CbT,
                     u16* __restrict__ Qwb, u16* __restrict__ QbT,
                     float* __restrict__ sub0, float* __restrict__ sub1){
  __shared__ u16 tile[64][130];
  __shared__ float wl[128];
  int t = threadIdx.x, blk = blockIdx.x;
  int lane = t & 63;
  bool isC = blk < 512;
  if (t < 128) wl[t] = w4mlu[t];
  __syncthreads();
  float2 wv = reinterpret_cast<const float2*>(isC ? w4C : w4Q)[lane];
  if (isC) {
    int b = blk >> 5, ct = blk & 31, c0 = ct << 6;
    const float* src = C + ((size_t)(b*LC + c0))*DD;
    for (int k = 0; k < 16; ++k) {
      int idx = t + (k << 8);
      int r = idx >> 6, d2 = idx & 63;
      float2 v = reinterpret_cast<const float2*>(src + (size_t)r*DD)[d2];
      float sdot = v.x*wv.x + v.y*wv.y;
      #pragma unroll
      for (int o = 32; o > 0; o >>= 1) sdot += __shfl_xor(sdot, o);
      if (lane == 0) sub0[b*LC + c0 + r] = sdot;
      u16 h0 = f2bf(v.x), h1 = f2bf(v.y);
      size_t o = ((size_t)(b*LC + c0 + r))*DD + 2*d2;
      *reinterpret_cast<u32*>(Cb + o) = (u32)h0 | ((u32)h1 << 16);
      tile[r][2*d2]   = h0;
      tile[r][2*d2+1] = h1;
    }
    __syncthreads();
    for (int k = 0; k < 8; ++k) {
      int ch = t + (k << 8);
      int d = ch >> 4, c4 = (ch & 15) << 2;
      u32 lo = (u32)tile[c4][d]   | ((u32)tile[c4+1][d] << 16);
      u32 hi = (u32)tile[c4+2][d] | ((u32)tile[c4+3][d] << 16);
      uint2 u; u.x = lo; u.y = hi;
      *reinterpret_cast<uint2*>(CbT + ((size_t)(b*DD + d))*LC + c0 + c4) = u;
    }
  } else {
    int bq = blk - 512;
    int b = bq >> 3, qt = bq & 7, q0 = qt << 6;
    const float* src = Q + ((size_t)(b*LQ + q0))*DD;
    for (int k = 0; k < 16; ++k) {
      int idx = t + (k << 8);
      int r = idx >> 6, d2 = idx & 63;
      float2 v = reinterpret_cast<const float2*>(src + (size_t)r*DD)[d2];
      float sdot = v.x*wv.x + v.y*wv.y;
      #pragma unroll
      for (int o = 32; o > 0; o >>= 1) sdot += __shfl_xor(sdot, o);
      if (lane == 0) sub1[b*LQ + q0 + r] = sdot;
      float qw0 = v.x * wl[2*d2], qw1 = v.y * wl[2*d2+1];
      size_t o = ((size_t)(b*LQ + q0 + r))*DD + 2*d2;
      *reinterpret_cast<u32*>(Qwb + o) = (u32)f2bf(qw0) | ((u32)f2bf(qw1) << 16);
      tile[r][2*d2]   = f2bf(v.x);
      tile[r][2*d2+1] = f2bf(v.y);
    }
    __syncthreads();
    for (int k = 0; k < 8; ++k) {
      int ch = t + (k << 8);
      int d = ch >> 4, c4 = (ch & 15) << 2;
      u32 lo = (u32)tile[c4][d]   | ((u32)tile[c4+1][d] << 16);
      u32 hi = (u32)tile[c4+2][d] | ((u32)tile[c4+3][d] << 16);
      uint2 u; u.x = lo; u.y = hi;
      *reinterpret_cast<uint2*>(QbT + ((size_t)(b*DD + d))*LQ + q0 + c4) = u;
    }
  }
}

// ---------------- K1: flash column-softmax -> partial T ----------------
__global__ __launch_bounds__(256, 3)
void flashT(const u16* __restrict__ Qwb, const u16* __restrict__ Cb,
            const u16* __restrict__ CbT, const float* __restrict__ sub0,
            float* __restrict__ mPart, float* __restrict__ lPart,
            u16* __restrict__ TaccP){
  __shared__ __align__(16) u16 buf[128*128];
  __shared__ u16 Pl[64][136];
  int bid = blockIdx.x;
  int id = (bid & 7) * 256 + (bid >> 3);
  int b = id >> 7, qb = (id >> 4) & 7, sp = id & 15;
  int c0 = sp * 128;
  int w = threadIdx.x >> 6, l = threadIdx.x & 63;
  int lj = l & 15, lg = l >> 4;

  {
    const char* gb = (const char*)(Cb + ((size_t)(b*LC + c0))*DD);
    #pragma unroll
    for (int i = 0; i < 8; ++i) {
      int off = (w*8 + i)*1024 + l*16;
      int row = off >> 8, col = off & 255;
      int src = (row << 8) | (col ^ ((row & 7) << 4));
      GLOAD_LDS(gb + src, (char*)buf + off);
    }
  }
  const u16* Qrow = Qwb + ((size_t)(b*LQ + qb*64 + w*16 + lj))*DD;
  bf16x8 aq[4];
  #pragma unroll
  for (int k = 0; k < 4; ++k) aq[k] = ldb8(Qrow + k*32 + lg*8);
  float s0v[8];
  #pragma unroll
  for (int f = 0; f < 8; ++f) s0v[f] = sub0[b*LC + c0 + f*16 + lj];
  __syncthreads();

  f32x4 s[8];
  #pragma unroll
  for (int f = 0; f < 8; ++f) s[f] = (f32x4){0.f,0.f,0.f,0.f};
  #pragma unroll
  for (int ks = 0; ks < 4; ++ks) {
    #pragma unroll
    for (int f = 0; f < 8; ++f)
      s[f] = MFMA(aq[ks], ldb8(swz(buf, f*16 + lj, ks*64 + lg*16)), s[f]);
  }
  __syncthreads();

  {
    const char* gb = (const char*)CbT + ((size_t)b*DD)*LC*2 + (size_t)c0*2;
    #pragma unroll
    for (int i = 0; i < 8; ++i) {
      int off = (w*8 + i)*1024 + l*16;
      int row = off >> 8, col = off & 255;
      size_t src = (size_t)row*(LC*2) + (col ^ ((row & 7) << 4));
      GLOAD_LDS(gb + src, (char*)buf + off);
    }
  }

  float tm[4] = {-1e30f,-1e30f,-1e30f,-1e30f};
  #pragma unroll
  for (int f = 0; f < 8; ++f) {
    #pragma unroll
    for (int r = 0; r < 4; ++r) { s[f][r] += s0v[f]; tm[r] = fmaxf(tm[r], s[f][r]); }
  }
  #pragma unroll
  for (int r = 0; r < 4; ++r) {
    #pragma unroll
    for (int m = 1; m < 16; m <<= 1) tm[r] = fmaxf(tm[r], __shfl_xor(tm[r], m));
  }
  float psum[4] = {0.f,0.f,0.f,0.f};
  #pragma unroll
  for (int f = 0; f < 8; ++f) {
    #pragma unroll
    for (int r = 0; r < 4; ++r) {
      float p = exp2f((s[f][r] - tm[r]) * L2E);
      psum[r] += p;
      Pl[w*16 + lg*4 + r][f*16 + lj] = f2bf(p);
    }
  }
  #pragma unroll
  for (int r = 0; r < 4; ++r) {
    #pragma unroll
    for (int m = 1; m < 16; m <<= 1) psum[r] += __shfl_xor(psum[r], m);
  }
  int pbase = (b*8 + qb)*SP + sp;
  if (lj == 0) {
    #pragma unroll
    for (int r = 0; r < 4; ++r) {
      mPart[pbase*64 + w*16 + lg*4 + r] = tm[r];
      lPart[pbase*64 + w*16 + lg*4 + r] = psum[r];
    }
  }
  __syncthreads();

  f32x4 tacc[8];
  #pragma unroll
  for (int f = 0; f < 8; ++f) tacc[f] = (f32x4){0.f,0.f,0.f,0.f};
  #pragma unroll
  for (int ks = 0; ks < 4; ++ks) {
    bf16x8 ap = *reinterpret_cast<const bf16x8*>(&Pl[w*16 + lj][ks*32 + lg*8]);
    #pragma unroll
    for (int f = 0; f < 8; ++f)
      tacc[f] = MFMA(ap, ldb8(swz(buf, f*16 + lj, ks*64 + lg*16)), tacc[f]);
  }
  #pragma unroll
  for (int f = 0; f < 8; ++f) {
    ushort4 hv;
    hv.x = f2bf(tacc[f][0]); hv.y = f2bf(tacc[f][1]);
    hv.z = f2bf(tacc[f][2]); hv.w = f2bf(tacc[f][3]);
    *reinterpret_cast<ushort4*>(TaccP + (((size_t)pbase*4 + w)*8 + f)*256 + lj*16 + lg*4) = hv;
  }
}

// ---------------- K1b: combine c-split partials -> TbT ----------------
__global__ void combineT(const float* __restrict__ mPart, const float* __restrict__ lPart,
                         const u16* __restrict__ TaccP, u16* __restrict__ TbT){
  __shared__ float fac[SP][64];
  __shared__ u16 Tt[64][68];
  int blk = blockIdx.x;
  int b = blk >> 4, qb = (blk >> 1) & 7, dh = blk & 1;
  int t = threadIdx.x;
  int base = (b*8 + qb)*SP;
  if (t < 64) {
    float m_[SP], mm = -1e30f;
    #pragma unroll
    for (int p = 0; p < SP; ++p) { m_[p] = mPart[(base+p)*64 + t]; mm = fmaxf(mm, m_[p]); }
    float lt = 0.f, e[SP];
    #pragma unroll
    for (int p = 0; p < SP; ++p) {
      e[p] = exp2f((m_[p] - mm) * L2E);
      lt += lPart[(base+p)*64 + t] * e[p];
    }
    float il = 1.0f / lt;
    #pragma unroll
    for (int p = 0; p < SP; ++p) fac[p][t] = e[p] * il;
  }
  __syncthreads();
  int lj = t >> 4, lg = (t >> 2) & 3, r = t & 3;
  for (int w = 0; w < 4; ++w) {
    int q = w*16 + lg*4 + r;
    for (int fi = 0; fi < 4; ++fi) {
      int f = dh*4 + fi;
      float acc = 0.f;
      #pragma unroll
      for (int p = 0; p < SP; ++p)
        acc += bf2f(TaccP[(((size_t)(base+p)*4 + w)*8 + f)*256 + t]) * fac[p][q];
      Tt[q][fi*16 + lj] = f2bf(acc);
    }
  }
  __syncthreads();
  for (int k = 0; k < 4; ++k) {
    int ch = t + (k << 8); int dl = ch >> 4, q4 = (ch & 15) << 2;
    u32 lo = (u32)Tt[q4][dl]   | ((u32)Tt[q4+1][dl] << 16);
    u32 hi = (u32)Tt[q4+2][dl] | ((u32)Tt[q4+3][dl] << 16);
    uint2 u; u.x = lo; u.y = hi;
    *reinterpret_cast<uint2*>(TbT + ((size_t)(b*DD + dh*64 + dl))*LQ + qb*64 + q4) = u;
  }
}

// ---------------- K2: flash row-softmax + A + Bt + epilogue ----------------
// grid 512 = 16 b x 32 ctiles(64 c). 4 waves; wave owns c = c0 + w*16 + lj.
// Online softmax over q in 8 chunks of 64. Orientation D[d][c]: softmax state
// (m, l, rescale) is lane-local; epilogue regs are 4 consecutive d -> float4.
__global__ __launch_bounds__(256, 2)
void rowflash(const float* __restrict__ Cf, const u16* __restrict__ Cb,
              const u16* __restrict__ Qwb, const u16* __restrict__ QbT,
              const u16* __restrict__ TbT, const float* __restrict__ sub1,
              float* __restrict__ out){
  __shared__ __align__(16) char smem[57344];
  char* sQw = smem;             // [64 q][256B] swz
  char* sQt = smem + 16384;     // [128 d][128B] swz
  char* sTt = smem + 32768;     // [128 d][128B] swz
  char* sPl = smem + 49152;     // [64 c][128B] swz (per-wave-private rows)

  int bid = blockIdx.x;
  int id = (bid & 7) * 64 + (bid >> 3);   // XCD swizzle, nwg=512
  int b = id >> 5, ct = id & 31, c0 = ct * 64;
  int tid = threadIdx.x;
  int w = tid >> 6, l = tid & 63;
  int lj = l & 15, lg = l >> 4;

  const char* gQw = (const char*)Qwb + (size_t)(b*LQ)*256;
  const char* gQt = (const char*)QbT + (size_t)(b*DD)*1024;
  const char* gTt = (const char*)TbT + (size_t)(b*DD)*1024;

  // resident QK B-frags: B[k=d][col=c], c = c0 + w*16 + lj
  bf16x8 ca[4];
  #pragma unroll
  for (int ks = 0; ks < 4; ++ks)
    ca[ks] = ldb8(Cb + ((size_t)(b*LC + c0 + w*16 + lj))*DD + ks*32 + lg*8);

  // prologue: stage chunk 0 of all three streams
  #pragma unroll
  for (int i = 0; i < 4; ++i) {
    int off = i*4096 + tid*16;
    { int row = off >> 8, col = off & 255;
      GLOAD_LDS(gQw + (size_t)row*256 + (col ^ ((row & 7) << 4)), sQw + off); }
    { int row = off >> 7, col = off & 127;
      size_t src = (size_t)row*1024 + (col ^ ((row & 7) << 4));
      GLOAD_LDS(gQt + src, sQt + off);
      GLOAD_LDS(gTt + src, sTt + off); }
  }

  float mrun = -1e30f, lrun = 0.f;
  f32x4 aA[8], aB[8];
  #pragma unroll
  for (int df = 0; df < 8; ++df) { aA[df] = (f32x4){0.f,0.f,0.f,0.f}; aB[df] = (f32x4){0.f,0.f,0.f,0.f}; }

  int crow = w*16 + lj;
  __syncthreads();   // chunk-0 stages drained

  for (int ch = 0; ch < 8; ++ch) {
    // ---- QK: S_chunk[q][c], per wave 4 qfrags x its 16 c
    f32x4 s4[4];
    #pragma unroll
    for (int qf = 0; qf < 4; ++qf) s4[qf] = (f32x4){0.f,0.f,0.f,0.f};
    #pragma unroll
    for (int qf = 0; qf < 4; ++qf) {
      int qr = qf*16 + lj;
      #pragma unroll
      for (int ks = 0; ks < 4; ++ks) {
        bf16x8 aq = ldb8((const u16*)(sQw + qr*256 + ((ks*64 + lg*16) ^ ((qr & 7) << 4))));
        s4[qf] = MFMA(aq, ca[ks], s4[qf]);
      }
    }
    // ---- online softmax (all lane-local in c)
    float tm = -1e30f;
    #pragma unroll
    for (int qf = 0; qf < 4; ++qf) {
      f32x4 sv = *reinterpret_cast<const f32x4*>(sub1 + b*LQ + ch*64 + qf*16 + lg*4);
      s4[qf] += sv;
      #pragma unroll
      for (int r = 0; r < 4; ++r) tm = fmaxf(tm, s4[qf][r]);
    }
    tm = fmaxf(tm, __shfl_xor(tm, 16));
    tm = fmaxf(tm, __shfl_xor(tm, 32));
    float mn = fmaxf(mrun, tm);
    float fsc = exp2f((mrun - mn) * L2E);
    mrun = mn;
    lrun *= fsc;
    #pragma unroll
    for (int df = 0; df < 8; ++df) { aA[df] *= fsc; aB[df] *= fsc; }
    float psum = 0.f;
    #pragma unroll
    for (int qf = 0; qf < 4; ++qf) {
      ushort4 hv;
      #pragma unroll
      for (int r = 0; r < 4; ++r) {
        float p = exp2f((s4[qf][r] - mrun) * L2E);
        psum += p;
        ((u16*)&hv)[r] = f2bf(p);
      }
      *reinterpret_cast<ushort4*>(sPl + crow*128 + ((qf*32 + lg*8) ^ ((crow & 7) << 4))) = hv;
    }
    psum += __shfl_xor(psum, 16);
    psum += __shfl_xor(psum, 32);
    lrun += psum;

    __syncthreads();   // barrier 1: QK reads of sQw done; drains Qt/Tt(ch) too
    if (ch < 7) {      // issue Qw(ch+1) -> lands before barrier 2's drain
      #pragma unroll
      for (int i = 0; i < 4; ++i) {
        int off = i*4096 + tid*16, row = off >> 8, col = off & 255;
        GLOAD_LDS(gQw + (size_t)(ch+1)*16384 + row*256 + (col ^ ((row & 7) << 4)), sQw + off);
      }
    }
    // ---- PV: aA[d][c] += Qt[d][q] P[c][q] ; aB from Tt
    bf16x8 pb[2];
    #pragma unroll
    for (int ks2 = 0; ks2 < 2; ++ks2)
      pb[ks2] = ldb8((const u16*)(sPl + crow*128 + ((ks2*64 + lg*16) ^ ((crow & 7) << 4))));
    #pragma unroll
    for (int df = 0; df < 8; ++df) {
      int dr = df*16 + lj;
      int sw = (dr & 7) << 4;
      #pragma unroll
      for (int ks2 = 0; ks2 < 2; ++ks2) {
        int cb = (ks2*64 + lg*16) ^ sw;
        bf16x8 at = ldb8((const u16*)(sQt + dr*128 + cb));
        aA[df] = MFMA(at, pb[ks2], aA[df]);
        bf16x8 bt = ldb8((const u16*)(sTt + dr*128 + cb));
        aB[df] = MFMA(bt, pb[ks2], aB[df]);
      }
    }
    __syncthreads();   // barrier 2: PV reads done; drains Qw(ch+1)
    if (ch < 7) {      // issue Qt/Tt(ch+1) -> drained at next barrier 1
      #pragma unroll
      for (int i = 0; i < 4; ++i) {
        int off = i*4096 + tid*16, row = off >> 7, col = off & 127;
        size_t src = (size_t)row*1024 + (ch+1)*128 + (col ^ ((row & 7) << 4));
        GLOAD_LDS(gQt + src, sQt + off);
        GLOAD_LDS(gTt + src, sTt + off);
      }
    }
  }

  // ---- epilogue: lane-local normalize; float4 stores (4 consecutive d)
  float linv = 1.0f / lrun;
  size_t rowb = (size_t)(b*LC + c0 + w*16 + lj);
  const float4* cfp = reinterpret_cast<const float4*>(Cf + rowb*DD);
  float4* op = reinterpret_cast<float4*>(out + rowb*512);
  #pragma unroll
  for (int df = 0; df < 8; ++df) {
    int dq = df*4 + lg;                   // float4 index: d = df*16 + lg*4
    float4 Cv = cfp[dq];
    float4 Av, Bv, CA, CB;
    Av.x = aA[df][0]*linv; Av.y = aA[df][1]*linv; Av.z = aA[df][2]*linv; Av.w = aA[df][3]*linv;
    Bv.x = aB[df][0]*linv; Bv.y = aB[df][1]*linv; Bv.z = aB[df][2]*linv; Bv.w = aB[df][3]*linv;
    CA.x = Cv.x*Av.x; CA.y = Cv.y*Av.y; CA.z = Cv.z*Av.z; CA.w = Cv.w*Av.w;
    CB.x = Cv.x*Bv.x; CB.y = Cv.y*Bv.y; CB.z = Cv.z*Bv.z; CB.w = Cv.w*Bv.w;
    op[dq]      = Cv;
    op[32 + dq] = Av;
    op[64 + dq] = CA;
    op[96 + dq] = CB;
  }
}

// ---------------- launch ----------------
extern "C" void kernel_launch(void* const* d_in, const int* in_sizes, int n_in,
                              void* d_out, int out_size, void* d_ws, size_t ws_size,
                              hipStream_t stream) {
  const float* C     = (const float*)d_in[0];
  const float* Q     = (const float*)d_in[1];
  const float* w4C   = (const float*)d_in[4];
  const float* w4Q   = (const float*)d_in[5];
  const float* w4mlu = (const float*)d_in[6];
  float* out = (float*)d_out;

  char* ws = (char*)d_ws;
  size_t off = 0;
  auto alloc = [&](size_t bytes) -> void* {
    void* p = ws + off;
    off += (bytes + 255) & ~(size_t)255;
    return p;
  };
  float* sub0  = (float*)alloc((size_t)B_*LC*4);
  float* sub1  = (float*)alloc((size_t)B_*LQ*4);
  u16*   Cb    = (u16*)  alloc((size_t)B_*LC*DD*2);
  u16*   CbT   = (u16*)  alloc((size_t)B_*DD*LC*2);
  u16*   Qwb   = (u16*)  alloc((size_t)B_*LQ*DD*2);
  u16*   QbT   = (u16*)  alloc((size_t)B_*DD*LQ*2);
  u16*   TbT   = (u16*)  alloc((size_t)B_*DD*LQ*2);
  float* mPart = (float*)alloc((size_t)B_*8*SP*64*4);
  float* lPart = (float*)alloc((size_t)B_*8*SP*64*4);
  u16*   TaccP = (u16*)  alloc((size_t)B_*8*SP*64*DD*2);

  hipLaunchKernelGGL(prep, dim3(640), dim3(256), 0, stream,
                     C, Q, w4C, w4Q, w4mlu, Cb, CbT, Qwb, QbT, sub0, sub1);
  hipLaunchKernelGGL(flashT, dim3(2048), dim3(256), 0, stream,
                     Qwb, Cb, CbT, sub0, mPart, lPart, TaccP);
  hipLaunchKernelGGL(combineT, dim3(256), dim3(256), 0, stream,
                     mPart, lPart, TaccP, TbT);
  hipLaunchKernelGGL(rowflash, dim3(512), dim3(256), 0, stream,
                     C, Cb, Qwb, QbT, TbT, sub1, out);
}